// Round 2
// baseline (624.903 us; speedup 1.0000x reference)
//
#include <hip/hip_runtime.h>
#include <stdint.h>

#define NN 50000
#define NE 800000
#define NB 196        // ceil(NN/256)
#define CAST_B 6250   // NN*128/4/256 exactly
#define CVTW_B 512    // 8*16384/256
#define CNT_B 3125    // NE/256 exactly
#define NX 8          // XCDs / histogram copies
#define NCH 4         // feature chunks (32 dims = 64B per row-chunk; slab 3.2MB < 4MB L2)

typedef short short8 __attribute__((ext_vector_type(8)));
typedef float f32x4 __attribute__((ext_vector_type(4)));
typedef unsigned int uint;
typedef unsigned short ushort;

// bf16 feature tensors are CHUNK-MAJOR: [NCH][NN][32]. One chunk slab =
// 50000*32*2B = 3.2MB -> L2-resident per XCD during aggregation.
#define SLAB_U (NN * 16)         // uints per chunk slab
#define SLAB_S (NN * 32)         // ushorts per chunk slab

__device__ __forceinline__ uint rne_bf16(float f) {
    uint x = __float_as_uint(f);
    return (x + 0x7FFFu + ((x >> 16) & 1u)) >> 16;  // round-to-nearest-even
}
__device__ __forceinline__ float bf_lo(uint d) { return __uint_as_float(d << 16); }
__device__ __forceinline__ float bf_hi(uint d) { return __uint_as_float(d & 0xFFFF0000u); }

// int64 edge_index => int32 view is [lo,hi,lo,hi,...] with hi==0 (vals<50000).
// For int32 data these words are random node ids; P(all 4 zero) ~ 2e-19.
__device__ __forceinline__ int ei_is64(const int* __restrict__ ei) {
    return (ei[1] | ei[3] | ei[5] | ei[7]) == 0;
}

__device__ __forceinline__ int xcc_id() {
    int x;
    asm volatile("s_getreg_b32 %0, hwreg(HW_REG_XCC_ID, 0, 32)" : "=s"(x));
    return x & (NX - 1);
}

struct Ptrs8 { const float* p[8]; };

// ---------------- packed prep: x-cast | W-cast | degree count -----------------
// NOTE (R1 post-mortem): XCD-local workgroup-scope atomics did NOT avoid the
// ~25.6MB (800k x 32B) atomic write-through (WRITE_SIZE unchanged) -- gfx950
// services global atomics memory-side regardless of scope. Kept because it is
// perf-neutral and the per-copy bases are already plumbed; the real fix (sort-
// based CSR build, no atomics) is a separate ~25us lever.
__global__ __launch_bounds__(256) void k_prep(
    const float* __restrict__ x, ushort* __restrict__ xbf, Ptrs8 ps,
    ushort* __restrict__ wbf, const int* __restrict__ ei,
    int* __restrict__ hist, uint* __restrict__ rank) {
    int b = blockIdx.x;
    if (b < CAST_B) {                       // cast x -> bf16, chunk-major
        int i = b * 256 + threadIdx.x;      // uint2 index; i < NN*32
        float4 v = ((const float4*)x)[i];
        uint2 o;
        o.x = rne_bf16(v.x) | (rne_bf16(v.y) << 16);
        o.y = rne_bf16(v.z) | (rne_bf16(v.w) << 16);
        int node = i >> 5;
        int chunk = (i >> 3) & 3;
        int w = i & 7;
        ((uint2*)xbf)[((size_t)chunk * NN + node) * 8 + w] = o;
    } else if (b < CAST_B + CVTW_B) {       // cast 8 weight matrices -> bf16
        int idx = (b - CAST_B) * 256 + threadIdx.x;
        int m = idx >> 14;
        int off = idx & 16383;
        wbf[idx] = (ushort)rne_bf16(ps.p[m][off]);
    } else {                                // degree count + arrival rank
        int e = (b - CAST_B - CVTW_B) * 256 + threadIdx.x;
        int is64 = ei_is64(ei);
        int d = is64 ? ei[2 * NE + 2 * e] : ei[NE + e];
        int cid = xcc_id();
        int rk = __hip_atomic_fetch_add(&hist[cid * NN + d], 1,
                                        __ATOMIC_RELAXED,
                                        __HIP_MEMORY_SCOPE_WORKGROUP);
        rank[e] = (uint)rk | ((uint)cid << 16);
    }
}

// ---------------- multi-block scan over deg -> row_ptr ----------------
__global__ __launch_bounds__(256) void k_blocksum(int* __restrict__ hist,
                                                  int* __restrict__ deg,
                                                  int* __restrict__ bsum) {
    __shared__ int s[256];
    int i = blockIdx.x * 256 + threadIdx.x;
    int sum = 0;
    if (i < NN) {
        int run = 0;
#pragma unroll
        for (int c = 0; c < NX; c++) {
            int t = hist[c * NN + i];
            hist[c * NN + i] = run;  // exclusive base for copy c
            run += t;
        }
        deg[i] = run;
        sum = run;
    }
    s[threadIdx.x] = sum;
    __syncthreads();
    for (int off = 128; off > 0; off >>= 1) {
        if (threadIdx.x < off) s[threadIdx.x] += s[threadIdx.x + off];
        __syncthreads();
    }
    if (threadIdx.x == 0) bsum[blockIdx.x] = s[0];
}

__global__ __launch_bounds__(256) void k_scanb(const int* __restrict__ bsum,
                                               int* __restrict__ boff) {
    __shared__ int s[256];
    int t = threadIdx.x;
    s[t] = (t < NB) ? bsum[t] : 0;
    __syncthreads();
    for (int off = 1; off < 256; off <<= 1) {
        int v = s[t];
        int a = (t >= off) ? s[t - off] : 0;
        __syncthreads();
        s[t] = v + a;
        __syncthreads();
    }
    if (t < NB) boff[t] = (t == 0) ? 0 : s[t - 1];
}

__global__ __launch_bounds__(256) void k_writeptr(const int* __restrict__ deg,
                                                  const int* __restrict__ boff,
                                                  const int* __restrict__ hist,
                                                  int* __restrict__ row_ptr,
                                                  int* __restrict__ rowb,
                                                  float* __restrict__ rinv) {
    __shared__ int s[256];
    int b = blockIdx.x, t = threadIdx.x;
    int i = b * 256 + t;
    int d = (i < NN) ? deg[i] : 0;
    s[t] = d;
    __syncthreads();
    for (int off = 1; off < 256; off <<= 1) {
        int v = s[t];
        int a = (t >= off) ? s[t - off] : 0;
        __syncthreads();
        s[t] = v + a;
        __syncthreads();
    }
    if (i < NN) {
        int pos = boff[b] + s[t] - d;
        row_ptr[i] = pos;
        rinv[i] = 1.0f / (float)max(d, 1);
#pragma unroll
        for (int c = 0; c < NX; c++) rowb[c * NN + i] = pos + hist[c * NN + i];
    }
    if (b == 0 && t == 0) row_ptr[NN] = NE;
}

// deterministic fill: p = rowb[copy][dst] + local_rank; no atomics.
__global__ void k_fill(const int* __restrict__ ei,
                       const int* __restrict__ rowb,
                       const uint* __restrict__ rank, ushort* __restrict__ col) {
    int e = blockIdx.x * 256 + threadIdx.x;
    if (e >= NE) return;
    int is64 = ei_is64(ei);
    int sv = is64 ? ei[2 * e] : ei[e];
    int dv = is64 ? ei[2 * NE + 2 * e] : ei[NE + e];
    uint r = rank[e];
    int p = rowb[(int)(r >> 16) * NN + dv] + (int)(r & 0xFFFFu);
    col[p] = (ushort)sv;
}

// ---------------- mean aggregation: feature-split, L2-resident ---------------
// Wave = (node, chunk). chunk = blockIdx%4 so the round-robin block->XCD map
// pins each XCD to ONE 3.2MB chunk slab -> gathers become L2 hits (previous
// structure: 205MB of random 256B rows vs 12.8MB working set = L3-latency
// bound at ~40us/layer). 16 lanes per edge, 4 edges per vector load; col and
// mean use non-temporal ops so the slab stays resident.
__global__ __launch_bounds__(256) void k_agg4(const ushort* __restrict__ h,
                                              const int* __restrict__ row_ptr,
                                              const ushort* __restrict__ col,
                                              const float* __restrict__ rinv,
                                              ushort* __restrict__ mean) {
    int chunk = blockIdx.x & 3;
    int node = (blockIdx.x >> 2) * 4 + (threadIdx.x >> 6);
    int lane = threadIdx.x & 63;
    int slot = lane >> 4;        // which of 4 edges
    int d = lane & 15;           // dim-pair within 32-dim chunk
    int beg = row_ptr[node], end = row_ptr[node + 1];
    const uint* hp = (const uint*)h + (size_t)chunk * SLAB_U;
    float a0 = 0.f, a1 = 0.f;
    for (int b = beg; b < end; b += 64) {
        int n = min(64, end - b);
        int cl = (int)__builtin_nontemporal_load(&col[b + min(lane, n - 1)]);
#pragma unroll 4
        for (int j0 = 0; j0 < n; j0 += 4) {
            int idx = j0 + slot;
            int s = __shfl(cl, min(idx, n - 1));   // per-lane bpermute
            uint v = hp[s * 16 + d];               // 64B L2-hit line per edge
            float m = (idx < n) ? 1.f : 0.f;
            a0 = fmaf(m, bf_lo(v), a0);
            a1 = fmaf(m, bf_hi(v), a1);
        }
    }
    // combine the 4 edge-slots (xor-16/32 preserves d)
    a0 += __shfl_xor(a0, 16); a0 += __shfl_xor(a0, 32);
    a1 += __shfl_xor(a1, 16); a1 += __shfl_xor(a1, 32);
    if (lane < 16) {
        float r = rinv[node];
        uint pk = rne_bf16(a0 * r) | (rne_bf16(a1 * r) << 16);
        __builtin_nontemporal_store(
            pk, (uint*)mean + ((size_t)chunk * NN + node) * 16 + lane);
    }
}

// ---------------- MFMA GEMM: out = mean@Wl^T + h@Wr^T + b (+ReLU) -------------
// A operands (mean, h) are chunk-major [4][NN][32]; W row-major [128][128].
__global__ __launch_bounds__(256) void k_gemm_mfma(
    const ushort* __restrict__ Am, const ushort* __restrict__ Ah,
    const ushort* __restrict__ Wlb, const ushort* __restrict__ Wrb,
    const float* __restrict__ bias, float* __restrict__ outf,
    ushort* __restrict__ outb, int relu) {
    const int lane = threadIdx.x & 63;
    const int wave = threadIdx.x >> 6;
    const int l15 = lane & 15;
    const int quad = lane >> 4;
    const int m0 = blockIdx.x * 64 + wave * 16;

    f32x4 acc[8];
#pragma unroll
    for (int t = 0; t < 8; t++) acc[t] = (f32x4){0.f, 0.f, 0.f, 0.f};

    int arow = min(m0 + l15, NN - 1);  // clamp loads; stores guarded below
    const ushort* Arm = Am + (size_t)arow * 32 + quad * 8;
    const ushort* Arh = Ah + (size_t)arow * 32 + quad * 8;
    const int wro = quad * 8;

#pragma unroll
    for (int half = 0; half < 2; half++) {
        const ushort* Ar = half ? Arh : Arm;
        const ushort* W = half ? Wrb : Wlb;
#pragma unroll
        for (int k0 = 0; k0 < 128; k0 += 32) {
            // chunk-major: dims [k0, k0+32) live in slab k0>>5
            short8 a = *(const short8*)(Ar + (size_t)(k0 >> 5) * SLAB_S);
#pragma unroll
            for (int t = 0; t < 8; t++) {
                short8 b = *(const short8*)(W + (size_t)(t * 16 + l15) * 128 + k0 + wro);
                acc[t] = __builtin_amdgcn_mfma_f32_16x16x32_bf16(a, b, acc[t], 0, 0, 0);
            }
        }
    }

    float bb[8];
#pragma unroll
    for (int t = 0; t < 8; t++) bb[t] = bias[t * 16 + l15];

#pragma unroll
    for (int r = 0; r < 4; r++) {
        int row = m0 + quad * 4 + r;  // C/D: row = quad*4 + reg
        if (row < NN) {
#pragma unroll
            for (int t = 0; t < 8; t++) {
                float v = acc[t][r] + bb[t];
                if (relu) v = fmaxf(v, 0.f);
                if (outb) {
                    // d = t*16+l15 -> chunk t>>1, within-chunk (t&1)*16+l15
                    outb[((size_t)(t >> 1) * NN + row) * 32 + (t & 1) * 16 + l15] =
                        (ushort)rne_bf16(v);
                } else {
                    outf[(size_t)row * 128 + t * 16 + l15] = v;  // fp32 row-major
                }
            }
        }
    }
}

extern "C" void kernel_launch(void* const* d_in, const int* in_sizes, int n_in,
                              void* d_out, int out_size, void* d_ws, size_t ws_size,
                              hipStream_t stream) {
    const float* x = (const float*)d_in[0];
    const int* ei = (const int*)d_in[1];
    const float* Wl[4] = {(const float*)d_in[2], (const float*)d_in[5],
                          (const float*)d_in[8], (const float*)d_in[11]};
    const float* bl[4] = {(const float*)d_in[3], (const float*)d_in[6],
                          (const float*)d_in[9], (const float*)d_in[12]};
    const float* Wr[4] = {(const float*)d_in[4], (const float*)d_in[7],
                          (const float*)d_in[10], (const float*)d_in[13]};
    float* out = (float*)d_out;

    char* p = (char*)d_ws;
    auto take = [&](size_t bytes) -> char* {
        char* r = p;
        p += (bytes + 255) & ~(size_t)255;
        return r;
    };
    int* hist = (int*)take((size_t)NX * NN * 4);   // per-XCD histograms -> bases
    int* deg = (int*)take(NN * 4);
    int* row_ptr = (int*)take((NN + 1) * 4);
    int* rowb = (int*)take((size_t)NX * NN * 4);   // row_ptr + per-copy base
    float* rinv = (float*)take(NN * 4);
    int* bsum = (int*)take(NB * 4);
    int* boff = (int*)take(NB * 4);
    uint* rank = (uint*)take((size_t)NE * 4);      // local rank | (copy<<16)
    ushort* col = (ushort*)take((size_t)NE * 2 + 256);  // +pad
    ushort* xbf = (ushort*)take((size_t)NN * 128 * 2);
    ushort* h1 = (ushort*)take((size_t)NN * 128 * 2);
    ushort* h2 = (ushort*)take((size_t)NN * 128 * 2);
    ushort* meanbf = (ushort*)take((size_t)NN * 128 * 2);
    ushort* wbf = (ushort*)take(8 * 16384 * 2);

    Ptrs8 ps;
    ps.p[0] = Wl[0]; ps.p[1] = Wr[0]; ps.p[2] = Wl[1]; ps.p[3] = Wr[1];
    ps.p[4] = Wl[2]; ps.p[5] = Wr[2]; ps.p[6] = Wl[3]; ps.p[7] = Wr[3];

    hipMemsetAsync(hist, 0, (size_t)NX * NN * 4, stream);
    k_prep<<<CAST_B + CVTW_B + CNT_B, 256, 0, stream>>>(x, xbf, ps, wbf, ei,
                                                        hist, rank);
    k_blocksum<<<NB, 256, 0, stream>>>(hist, deg, bsum);
    k_scanb<<<1, 256, 0, stream>>>(bsum, boff);
    k_writeptr<<<NB, 256, 0, stream>>>(deg, boff, hist, row_ptr, rowb, rinv);
    k_fill<<<CNT_B, 256, 0, stream>>>(ei, rowb, rank, col);

    const ushort* h = xbf;
    ushort* houts[4] = {h1, h2, h1, nullptr};  // final layer -> fp32 d_out
    for (int l = 0; l < 4; l++) {
        // grid = (NN/4 node-groups) x 4 chunks; chunk = blockIdx%4 for XCD pin
        k_agg4<<<(NN / 4) * NCH, 256, 0, stream>>>(h, row_ptr, col, rinv, meanbf);
        k_gemm_mfma<<<(NN + 63) / 64, 256, 0, stream>>>(
            meanbf, h, wbf + (size_t)(2 * l) * 16384,
            wbf + (size_t)(2 * l + 1) * 16384, bl[l], out, houts[l],
            l == 0 ? 1 : 0);
        h = houts[l];
    }
}

// Round 3
// 406.257 us; speedup vs baseline: 1.5382x; 1.5382x over previous
//
#include <hip/hip_runtime.h>
#include <stdint.h>

#define NN 50000
#define NE 800000
#define CAST_B 6250   // NN*128/4/256 exactly
#define CVTW_B 512    // 8*16384/256
#define EPB 8192      // edges per hist/scatter block
#define HIST_B 98     // ceil(NE/EPB)
#define NBK 196       // coarse buckets: dst>>8 (49999>>8 = 195)

typedef short short8 __attribute__((ext_vector_type(8)));
typedef float f32x4 __attribute__((ext_vector_type(4)));
typedef unsigned int uint;
typedef unsigned short ushort;

__device__ __forceinline__ uint rne_bf16(float f) {
    uint x = __float_as_uint(f);
    return (x + 0x7FFFu + ((x >> 16) & 1u)) >> 16;  // round-to-nearest-even
}
__device__ __forceinline__ float bf_lo(uint d) { return __uint_as_float(d << 16); }
__device__ __forceinline__ float bf_hi(uint d) { return __uint_as_float(d & 0xFFFF0000u); }

// int64 edge_index => int32 view is [lo,hi,lo,hi,...] with hi==0 (vals<50000).
// For int32 data these words are random node ids; P(all 4 zero) ~ 2e-19.
__device__ __forceinline__ int ei_is64(const int* __restrict__ ei) {
    return (ei[1] | ei[3] | ei[5] | ei[7]) == 0;
}

struct Ptrs8 { const float* p[8]; };

// -------- prep: x-cast | W-cast | edge pack + coarse histogram (LDS only) ----
// R0/R1 lesson: 800k global atomicAdds are serviced memory-side (~18 Gops/s,
// 25.6MB write-through) regardless of scope -> replaced by a 2-level bucket
// sort whose only atomics are LDS. This branch packs (dst<<16)|src (both
// <65536) and counts 196 coarse bins (dst>>8) per 8192-edge block.
__global__ __launch_bounds__(256) void k_prep(
    const float* __restrict__ x, ushort* __restrict__ xbf, Ptrs8 ps,
    ushort* __restrict__ wbf, const int* __restrict__ ei,
    uint* __restrict__ ebuf, int* __restrict__ hcnt) {
    __shared__ int hs[NBK];
    int b = blockIdx.x;
    if (b < CAST_B) {                       // cast x -> bf16 row-major
        int i = b * 256 + threadIdx.x;
        float4 v = ((const float4*)x)[i];
        uint2 o;
        o.x = rne_bf16(v.x) | (rne_bf16(v.y) << 16);
        o.y = rne_bf16(v.z) | (rne_bf16(v.w) << 16);
        ((uint2*)xbf)[i] = o;
    } else if (b < CAST_B + CVTW_B) {       // cast 8 weight matrices -> bf16
        int idx = (b - CAST_B) * 256 + threadIdx.x;
        int m = idx >> 14;
        int off = idx & 16383;
        wbf[idx] = (ushort)rne_bf16(ps.p[m][off]);
    } else {                                // pack edges + coarse hist
        int hb = b - CAST_B - CVTW_B;
        int t = threadIdx.x;
        for (int i = t; i < NBK; i += 256) hs[i] = 0;
        __syncthreads();
        int base = hb * EPB;
        int is64 = ei_is64(ei);
        for (int i = 0; i < EPB; i += 256) {
            int e = base + i + t;
            if (e < NE) {
                int sv = is64 ? ei[2 * e] : ei[e];
                int dv = is64 ? ei[2 * NE + 2 * e] : ei[NE + e];
                ebuf[e] = ((uint)dv << 16) | (uint)sv;
                atomicAdd(&hs[dv >> 8], 1);
            }
        }
        __syncthreads();
        for (int i = t; i < NBK; i += 256) hcnt[hb * NBK + i] = hs[i];
    }
}

// single block: bucket totals -> exclusive bases -> per-(block,bucket) offsets
__global__ __launch_bounds__(256) void k_scan1(const int* __restrict__ hcnt,
                                               int* __restrict__ hoff,
                                               int* __restrict__ bb,
                                               int* __restrict__ row_ptr) {
    __shared__ int s[256];
    int t = threadIdx.x;
    int tot = 0;
    if (t < NBK)
        for (int b = 0; b < HIST_B; b++) tot += hcnt[b * NBK + t];
    s[t] = tot;
    __syncthreads();
    for (int off = 1; off < 256; off <<= 1) {  // inclusive scan
        int v = s[t];
        int a = (t >= off) ? s[t - off] : 0;
        __syncthreads();
        s[t] = v + a;
        __syncthreads();
    }
    if (t < NBK) {
        int base = (t == 0) ? 0 : s[t - 1];  // exclusive
        bb[t] = base;
        int run = base;
        for (int b = 0; b < HIST_B; b++) {
            hoff[b * NBK + t] = run;
            run += hcnt[b * NBK + t];
        }
    }
    if (t == 0) { bb[NBK] = NE; row_ptr[NN] = NE; }
}

// coarse scatter: LDS rank counters, writes land in ~170B runs per bucket
__global__ __launch_bounds__(256) void k_scatter1(const uint* __restrict__ ebuf,
                                                  const int* __restrict__ hoff,
                                                  uint* __restrict__ ebuf2) {
    __shared__ int pos[NBK];
    int hb = blockIdx.x, t = threadIdx.x;
    for (int i = t; i < NBK; i += 256) pos[i] = hoff[hb * NBK + i];
    __syncthreads();
    int base = hb * EPB;
    for (int i = 0; i < EPB; i += 256) {
        int e = base + i + t;
        if (e < NE) {
            uint pk = ebuf[e];
            int idx = atomicAdd(&pos[pk >> 24], 1);
            ebuf2[idx] = pk;
        }
    }
}

// per-bucket counting sort: one block per 256-node bucket (~4k edges), two
// passes over its global range; emits col (src) and row_ptr directly.
__global__ __launch_bounds__(1024) void k_sort2(const uint* __restrict__ ebuf2,
                                                const int* __restrict__ bb,
                                                int* __restrict__ row_ptr,
                                                ushort* __restrict__ col) {
    __shared__ int hist[256];
    __shared__ int pos[256];
    int k = blockIdx.x, t = threadIdx.x;
    int beg = bb[k], end = bb[k + 1];
    if (t < 256) hist[t] = 0;
    __syncthreads();
    for (int j = beg + t; j < end; j += 1024)
        atomicAdd(&hist[(ebuf2[j] >> 16) & 255], 1);
    __syncthreads();
    for (int off = 1; off < 256; off <<= 1) {  // inclusive scan (1024-thr safe)
        int v = 0;
        if (t < 256) { v = hist[t]; if (t >= off) v += hist[t - off]; }
        __syncthreads();
        if (t < 256) hist[t] = v;
        __syncthreads();
    }
    if (t < 256) {
        int ex = (t == 0) ? 0 : hist[t - 1];
        pos[t] = beg + ex;
        int node = k * 256 + t;
        if (node < NN) row_ptr[node] = beg + ex;
    }
    __syncthreads();
    for (int j = beg + t; j < end; j += 1024) {
        uint pk = ebuf2[j];
        int idx = atomicAdd(&pos[(pk >> 16) & 255], 1);
        col[idx] = (ushort)(pk & 0xFFFFu);
    }
}

// ---------------- mean aggregation (measured-best structure, R1) -------------
// One wave per node; lane = bf16 pair. One col load covers 64 edges; row
// gathers are independent 256B coalesced wave loads. ~40us/layer = 5.1 TB/s
// effective on 205MB of gathers (~80% of streaming ceiling) -> near-floor.
// R2 lesson: feature-split (64B/edge L2-resident variant) regressed 2x --
// per-wave overhead quadrupled at avg degree 16. Keep this structure.
__global__ __launch_bounds__(256) void k_agg3(const ushort* __restrict__ h,
                                              const int* __restrict__ row_ptr,
                                              const ushort* __restrict__ col,
                                              ushort* __restrict__ mean) {
    int node = blockIdx.x * 4 + (threadIdx.x >> 6);
    if (node >= NN) return;
    int lane = threadIdx.x & 63;
    int beg = row_ptr[node], end = row_ptr[node + 1];
    const uint* hp = (const uint*)h;  // row = 64 uints (128 bf16)
    float a0 = 0.f, a1 = 0.f;
    for (int b = beg; b < end; b += 64) {   // one iteration for deg <= 64
        int n = min(64, end - b);
        int c = (int)col[b + min(lane, n - 1)];
        for (int j0 = 0; j0 < n; j0 += 8) {
#pragma unroll
            for (int j = 0; j < 8; j++) {
                int jj = j0 + j;                     // wave-uniform
                int s = __shfl(c, min(jj, n - 1));   // uniform broadcast
                uint v = hp[s * 64 + lane];          // coalesced 256B row
                float m = (jj < n) ? 1.f : 0.f;
                a0 = fmaf(m, bf_lo(v), a0);
                a1 = fmaf(m, bf_hi(v), a1);
            }
        }
    }
    float r = 1.0f / (float)max(end - beg, 1);  // deg from row_ptr: free rinv
    ((uint*)mean)[node * 64 + lane] = rne_bf16(a0 * r) | (rne_bf16(a1 * r) << 16);
}

// ---------------- MFMA GEMM: out = mean@Wl^T + h@Wr^T + b (+ReLU) -------------
__global__ __launch_bounds__(256) void k_gemm_mfma(
    const ushort* __restrict__ Am, const ushort* __restrict__ Ah,
    const ushort* __restrict__ Wlb, const ushort* __restrict__ Wrb,
    const float* __restrict__ bias, float* __restrict__ outf,
    ushort* __restrict__ outb, int relu) {
    const int lane = threadIdx.x & 63;
    const int wave = threadIdx.x >> 6;
    const int l15 = lane & 15;
    const int quad = lane >> 4;
    const int m0 = blockIdx.x * 64 + wave * 16;

    f32x4 acc[8];
#pragma unroll
    for (int t = 0; t < 8; t++) acc[t] = (f32x4){0.f, 0.f, 0.f, 0.f};

    int arow = min(m0 + l15, NN - 1);  // clamp loads; stores guarded below
    const ushort* Arm = Am + (size_t)arow * 128 + quad * 8;
    const ushort* Arh = Ah + (size_t)arow * 128 + quad * 8;
    const int wro = quad * 8;

#pragma unroll
    for (int half = 0; half < 2; half++) {
        const ushort* Ar = half ? Arh : Arm;
        const ushort* W = half ? Wrb : Wlb;
#pragma unroll
        for (int k0 = 0; k0 < 128; k0 += 32) {
            short8 a = *(const short8*)(Ar + k0);
#pragma unroll
            for (int t = 0; t < 8; t++) {
                short8 b = *(const short8*)(W + (size_t)(t * 16 + l15) * 128 + k0 + wro);
                acc[t] = __builtin_amdgcn_mfma_f32_16x16x32_bf16(a, b, acc[t], 0, 0, 0);
            }
        }
    }

    float bb[8];
#pragma unroll
    for (int t = 0; t < 8; t++) bb[t] = bias[t * 16 + l15];

#pragma unroll
    for (int r = 0; r < 4; r++) {
        int row = m0 + quad * 4 + r;  // C/D: row = quad*4 + reg
        if (row < NN) {
#pragma unroll
            for (int t = 0; t < 8; t++) {
                float v = acc[t][r] + bb[t];
                if (relu) v = fmaxf(v, 0.f);
                if (outb) outb[(size_t)row * 128 + t * 16 + l15] = (ushort)rne_bf16(v);
                else outf[(size_t)row * 128 + t * 16 + l15] = v;
            }
        }
    }
}

extern "C" void kernel_launch(void* const* d_in, const int* in_sizes, int n_in,
                              void* d_out, int out_size, void* d_ws, size_t ws_size,
                              hipStream_t stream) {
    const float* x = (const float*)d_in[0];
    const int* ei = (const int*)d_in[1];
    const float* Wl[4] = {(const float*)d_in[2], (const float*)d_in[5],
                          (const float*)d_in[8], (const float*)d_in[11]};
    const float* bl[4] = {(const float*)d_in[3], (const float*)d_in[6],
                          (const float*)d_in[9], (const float*)d_in[12]};
    const float* Wr[4] = {(const float*)d_in[4], (const float*)d_in[7],
                          (const float*)d_in[10], (const float*)d_in[13]};
    float* out = (float*)d_out;

    char* p = (char*)d_ws;
    auto take = [&](size_t bytes) -> char* {
        char* r = p;
        p += (bytes + 255) & ~(size_t)255;
        return r;
    };
    uint* ebuf = (uint*)take((size_t)NE * 4);
    uint* ebuf2 = (uint*)take((size_t)NE * 4);
    int* hcnt = (int*)take((size_t)HIST_B * NBK * 4);
    int* hoff = (int*)take((size_t)HIST_B * NBK * 4);
    int* bb = (int*)take((NBK + 1) * 4);
    int* row_ptr = (int*)take((NN + 1) * 4);
    ushort* col = (ushort*)take((size_t)NE * 2 + 256);  // +pad
    ushort* xbf = (ushort*)take((size_t)NN * 128 * 2);
    ushort* h1 = (ushort*)take((size_t)NN * 128 * 2);
    ushort* h2 = (ushort*)take((size_t)NN * 128 * 2);
    ushort* meanbf = (ushort*)take((size_t)NN * 128 * 2);
    ushort* wbf = (ushort*)take(8 * 16384 * 2);

    Ptrs8 ps;
    ps.p[0] = Wl[0]; ps.p[1] = Wr[0]; ps.p[2] = Wl[1]; ps.p[3] = Wr[1];
    ps.p[4] = Wl[2]; ps.p[5] = Wr[2]; ps.p[6] = Wl[3]; ps.p[7] = Wr[3];

    // CSR via 2-level bucket sort: no global atomics, no memset, no fill.
    k_prep<<<CAST_B + CVTW_B + HIST_B, 256, 0, stream>>>(x, xbf, ps, wbf, ei,
                                                         ebuf, hcnt);
    k_scan1<<<1, 256, 0, stream>>>(hcnt, hoff, bb, row_ptr);
    k_scatter1<<<HIST_B, 256, 0, stream>>>(ebuf, hoff, ebuf2);
    k_sort2<<<NBK, 1024, 0, stream>>>(ebuf2, bb, row_ptr, col);

    const ushort* h = xbf;
    ushort* houts[4] = {h1, h2, h1, nullptr};  // final layer -> fp32 d_out
    for (int l = 0; l < 4; l++) {
        k_agg3<<<(NN + 3) / 4, 256, 0, stream>>>(h, row_ptr, col, meanbf);
        k_gemm_mfma<<<(NN + 63) / 64, 256, 0, stream>>>(
            meanbf, h, wbf + (size_t)(2 * l) * 16384,
            wbf + (size_t)(2 * l + 1) * 16384, bl[l], out, houts[l],
            l == 0 ? 1 : 0);
        h = houts[l];
    }
}

// Round 4
// 353.591 us; speedup vs baseline: 1.7673x; 1.1489x over previous
//
#include <hip/hip_runtime.h>
#include <stdint.h>

#define NN 50000
#define NE 800000
#define CAST_B 6250   // NN*128/4/256 exactly
#define CVTW_B 512    // 8*16384/256
#define EPB 8192      // edges per hist/scatter block
#define HIST_B 98     // ceil(NE/EPB)
#define NBK 196       // coarse buckets: dst>>8 (49999>>8 = 195)

typedef short short8 __attribute__((ext_vector_type(8)));
typedef float f32x4 __attribute__((ext_vector_type(4)));
typedef unsigned int uint;
typedef unsigned short ushort;

__device__ __forceinline__ uint rne_bf16(float f) {
    uint x = __float_as_uint(f);
    return (x + 0x7FFFu + ((x >> 16) & 1u)) >> 16;  // round-to-nearest-even
}
__device__ __forceinline__ float bf_lo(uint d) { return __uint_as_float(d << 16); }
__device__ __forceinline__ float bf_hi(uint d) { return __uint_as_float(d & 0xFFFF0000u); }

// int64 edge_index => int32 view is [lo,hi,lo,hi,...] with hi==0 (vals<50000).
// For int32 data these words are random node ids; P(all 4 zero) ~ 2e-19.
__device__ __forceinline__ int ei_is64(const int* __restrict__ ei) {
    return (ei[1] | ei[3] | ei[5] | ei[7]) == 0;
}

struct Ptrs8 { const float* p[8]; };

// -------- prep: x-cast | W-cast (fragment-major) | edge pack + coarse hist ---
// R0/R1 lesson: 800k global atomicAdds are serviced memory-side (~18 Gops/s,
// 25.6MB write-through) regardless of scope -> 2-level LDS-atomic bucket sort.
// R4: W is cast into MFMA-FRAGMENT-MAJOR order so the GEMM's B loads are
// `base + lane*16B` (coalesced 1KB wave loads) instead of 64 lanes striding
// 256B over a 16KB window. Within matrix m: idx = ((k0i*8 + t)*64 + lane)*8+e
// holds W[r=t*16+(lane&15)][c=k0i*32+(lane>>4)*8+e].
__global__ __launch_bounds__(256) void k_prep(
    const float* __restrict__ x, ushort* __restrict__ xbf, Ptrs8 ps,
    ushort* __restrict__ wbf, const int* __restrict__ ei,
    uint* __restrict__ ebuf, int* __restrict__ hcnt) {
    __shared__ int hs[NBK];
    int b = blockIdx.x;
    if (b < CAST_B) {                       // cast x -> bf16 row-major
        int i = b * 256 + threadIdx.x;
        float4 v = ((const float4*)x)[i];
        uint2 o;
        o.x = rne_bf16(v.x) | (rne_bf16(v.y) << 16);
        o.y = rne_bf16(v.z) | (rne_bf16(v.w) << 16);
        ((uint2*)xbf)[i] = o;
    } else if (b < CAST_B + CVTW_B) {       // cast 8 W matrices, frag-major
        int idx = (b - CAST_B) * 256 + threadIdx.x;
        int m = idx >> 14;
        int o14 = idx & 16383;
        int k0i = (o14 >> 12) & 3;
        int t = (o14 >> 9) & 7;
        int lane6 = (o14 >> 3) & 63;
        int e = o14 & 7;
        int r = t * 16 + (lane6 & 15);
        int c = k0i * 32 + (lane6 >> 4) * 8 + e;
        wbf[idx] = (ushort)rne_bf16(ps.p[m][r * 128 + c]);
    } else {                                // pack edges + coarse hist
        int hb = b - CAST_B - CVTW_B;
        int t = threadIdx.x;
        for (int i = t; i < NBK; i += 256) hs[i] = 0;
        __syncthreads();
        int base = hb * EPB;
        int is64 = ei_is64(ei);
        for (int i = 0; i < EPB; i += 256) {
            int e = base + i + t;
            if (e < NE) {
                int sv = is64 ? ei[2 * e] : ei[e];
                int dv = is64 ? ei[2 * NE + 2 * e] : ei[NE + e];
                ebuf[e] = ((uint)dv << 16) | (uint)sv;
                atomicAdd(&hs[dv >> 8], 1);
            }
        }
        __syncthreads();
        for (int i = t; i < NBK; i += 256) hcnt[hb * NBK + i] = hs[i];
    }
}

// single block: bucket totals -> exclusive bases -> per-(block,bucket) offsets
__global__ __launch_bounds__(256) void k_scan1(const int* __restrict__ hcnt,
                                               int* __restrict__ hoff,
                                               int* __restrict__ bb,
                                               int* __restrict__ row_ptr) {
    __shared__ int s[256];
    int t = threadIdx.x;
    int tot = 0;
    if (t < NBK)
        for (int b = 0; b < HIST_B; b++) tot += hcnt[b * NBK + t];
    s[t] = tot;
    __syncthreads();
    for (int off = 1; off < 256; off <<= 1) {  // inclusive scan
        int v = s[t];
        int a = (t >= off) ? s[t - off] : 0;
        __syncthreads();
        s[t] = v + a;
        __syncthreads();
    }
    if (t < NBK) {
        int base = (t == 0) ? 0 : s[t - 1];  // exclusive
        bb[t] = base;
        int run = base;
        for (int b = 0; b < HIST_B; b++) {
            hoff[b * NBK + t] = run;
            run += hcnt[b * NBK + t];
        }
    }
    if (t == 0) { bb[NBK] = NE; row_ptr[NN] = NE; }
}

// coarse scatter: LDS rank counters, writes land in ~170B runs per bucket
__global__ __launch_bounds__(256) void k_scatter1(const uint* __restrict__ ebuf,
                                                  const int* __restrict__ hoff,
                                                  uint* __restrict__ ebuf2) {
    __shared__ int pos[NBK];
    int hb = blockIdx.x, t = threadIdx.x;
    for (int i = t; i < NBK; i += 256) pos[i] = hoff[hb * NBK + i];
    __syncthreads();
    int base = hb * EPB;
    for (int i = 0; i < EPB; i += 256) {
        int e = base + i + t;
        if (e < NE) {
            uint pk = ebuf[e];
            int idx = atomicAdd(&pos[pk >> 24], 1);
            ebuf2[idx] = pk;
        }
    }
}

// per-bucket counting sort: one block per 256-node bucket (~4k edges), two
// passes over its global range; emits col (src) and row_ptr directly.
__global__ __launch_bounds__(1024) void k_sort2(const uint* __restrict__ ebuf2,
                                                const int* __restrict__ bb,
                                                int* __restrict__ row_ptr,
                                                ushort* __restrict__ col) {
    __shared__ int hist[256];
    __shared__ int pos[256];
    int k = blockIdx.x, t = threadIdx.x;
    int beg = bb[k], end = bb[k + 1];
    if (t < 256) hist[t] = 0;
    __syncthreads();
    for (int j = beg + t; j < end; j += 1024)
        atomicAdd(&hist[(ebuf2[j] >> 16) & 255], 1);
    __syncthreads();
    for (int off = 1; off < 256; off <<= 1) {  // inclusive scan (1024-thr safe)
        int v = 0;
        if (t < 256) { v = hist[t]; if (t >= off) v += hist[t - off]; }
        __syncthreads();
        if (t < 256) hist[t] = v;
        __syncthreads();
    }
    if (t < 256) {
        int ex = (t == 0) ? 0 : hist[t - 1];
        pos[t] = beg + ex;
        int node = k * 256 + t;
        if (node < NN) row_ptr[node] = beg + ex;
    }
    __syncthreads();
    for (int j = beg + t; j < end; j += 1024) {
        uint pk = ebuf2[j];
        int idx = atomicAdd(&pos[(pk >> 16) & 255], 1);
        col[idx] = (ushort)(pk & 0xFFFFu);
    }
}

// ---------------- mean aggregation (measured-best structure, R1) -------------
// One wave per node; lane = bf16 pair. One col load covers 64 edges; row
// gathers are independent 256B coalesced wave loads. ~40us/layer = 5.1 TB/s
// effective on 205MB of gathers (~80% of random-line service ceiling).
// R2 lesson: feature-split (64B/edge L2-resident variant) regressed 2x --
// per-wave overhead quadrupled at avg degree 16. Keep this structure.
__global__ __launch_bounds__(256) void k_agg3(const ushort* __restrict__ h,
                                              const int* __restrict__ row_ptr,
                                              const ushort* __restrict__ col,
                                              ushort* __restrict__ mean) {
    int node = blockIdx.x * 4 + (threadIdx.x >> 6);
    if (node >= NN) return;
    int lane = threadIdx.x & 63;
    int beg = row_ptr[node], end = row_ptr[node + 1];
    const uint* hp = (const uint*)h;  // row = 64 uints (128 bf16)
    float a0 = 0.f, a1 = 0.f;
    for (int b = beg; b < end; b += 64) {   // one iteration for deg <= 64
        int n = min(64, end - b);
        int c = (int)col[b + min(lane, n - 1)];
        for (int j0 = 0; j0 < n; j0 += 8) {
#pragma unroll
            for (int j = 0; j < 8; j++) {
                int jj = j0 + j;                     // wave-uniform
                int s = __shfl(c, min(jj, n - 1));   // uniform broadcast
                uint v = hp[s * 64 + lane];          // coalesced 256B row
                float m = (jj < n) ? 1.f : 0.f;
                a0 = fmaf(m, bf_lo(v), a0);
                a1 = fmaf(m, bf_hi(v), a1);
            }
        }
    }
    float r = 1.0f / (float)max(end - beg, 1);  // deg from row_ptr: free rinv
    ((uint*)mean)[node * 64 + lane] = rne_bf16(a0 * r) | (rne_bf16(a1 * r) << 16);
}

// ------- MFMA GEMM: out = mean@Wl^T + h@Wr^T + b (+ReLU), 32 rows/wave -------
// R4: B operand (W) is fragment-major (see k_prep) -> every B load is a
// coalesced `base + lane*16B` 1KB wave load; each B fragment feeds 2 MFMAs
// (two 16-row A sets), halving B-load instruction count and B traffic.
__global__ __launch_bounds__(256) void k_gemm_mfma(
    const ushort* __restrict__ Am, const ushort* __restrict__ Ah,
    const ushort* __restrict__ Wlb, const ushort* __restrict__ Wrb,
    const float* __restrict__ bias, float* __restrict__ outf,
    ushort* __restrict__ outb, int relu) {
    const int lane = threadIdx.x & 63;
    const int wave = threadIdx.x >> 6;
    const int l15 = lane & 15;
    const int quad = lane >> 4;
    const int m0 = blockIdx.x * 128 + wave * 32;

    f32x4 acc[2][8];
#pragma unroll
    for (int s = 0; s < 2; s++)
#pragma unroll
        for (int t = 0; t < 8; t++) acc[s][t] = (f32x4){0.f, 0.f, 0.f, 0.f};

    int ar0 = min(m0 + l15, NN - 1);       // clamp loads; stores guarded below
    int ar1 = min(m0 + 16 + l15, NN - 1);
    const ushort* A0m = Am + (size_t)ar0 * 128 + quad * 8;
    const ushort* A1m = Am + (size_t)ar1 * 128 + quad * 8;
    const ushort* A0h = Ah + (size_t)ar0 * 128 + quad * 8;
    const ushort* A1h = Ah + (size_t)ar1 * 128 + quad * 8;

#pragma unroll
    for (int half = 0; half < 2; half++) {
        const ushort* W = half ? Wrb : Wlb;
        const ushort* A0 = half ? A0h : A0m;
        const ushort* A1 = half ? A1h : A1m;
#pragma unroll
        for (int k0 = 0; k0 < 128; k0 += 32) {
            short8 a0 = *(const short8*)(A0 + k0);
            short8 a1 = *(const short8*)(A1 + k0);
            const ushort* Wk = W + ((k0 >> 5) * 8) * 512 + lane * 8;
#pragma unroll
            for (int t = 0; t < 8; t++) {
                short8 b = *(const short8*)(Wk + t * 512);
                acc[0][t] = __builtin_amdgcn_mfma_f32_16x16x32_bf16(a0, b, acc[0][t], 0, 0, 0);
                acc[1][t] = __builtin_amdgcn_mfma_f32_16x16x32_bf16(a1, b, acc[1][t], 0, 0, 0);
            }
        }
    }

    float bb[8];
#pragma unroll
    for (int t = 0; t < 8; t++) bb[t] = bias[t * 16 + l15];

#pragma unroll
    for (int s = 0; s < 2; s++) {
#pragma unroll
        for (int r = 0; r < 4; r++) {
            int row = m0 + s * 16 + quad * 4 + r;  // C/D: row = quad*4 + reg
            if (row < NN) {
#pragma unroll
                for (int t = 0; t < 8; t++) {
                    float v = acc[s][t][r] + bb[t];
                    if (relu) v = fmaxf(v, 0.f);
                    if (outb) outb[(size_t)row * 128 + t * 16 + l15] = (ushort)rne_bf16(v);
                    else outf[(size_t)row * 128 + t * 16 + l15] = v;
                }
            }
        }
    }
}

extern "C" void kernel_launch(void* const* d_in, const int* in_sizes, int n_in,
                              void* d_out, int out_size, void* d_ws, size_t ws_size,
                              hipStream_t stream) {
    const float* x = (const float*)d_in[0];
    const int* ei = (const int*)d_in[1];
    const float* Wl[4] = {(const float*)d_in[2], (const float*)d_in[5],
                          (const float*)d_in[8], (const float*)d_in[11]};
    const float* bl[4] = {(const float*)d_in[3], (const float*)d_in[6],
                          (const float*)d_in[9], (const float*)d_in[12]};
    const float* Wr[4] = {(const float*)d_in[4], (const float*)d_in[7],
                          (const float*)d_in[10], (const float*)d_in[13]};
    float* out = (float*)d_out;

    char* p = (char*)d_ws;
    auto take = [&](size_t bytes) -> char* {
        char* r = p;
        p += (bytes + 255) & ~(size_t)255;
        return r;
    };
    uint* ebuf = (uint*)take((size_t)NE * 4);
    uint* ebuf2 = (uint*)take((size_t)NE * 4);
    int* hcnt = (int*)take((size_t)HIST_B * NBK * 4);
    int* hoff = (int*)take((size_t)HIST_B * NBK * 4);
    int* bb = (int*)take((NBK + 1) * 4);
    int* row_ptr = (int*)take((NN + 1) * 4);
    ushort* col = (ushort*)take((size_t)NE * 2 + 256);  // +pad
    ushort* xbf = (ushort*)take((size_t)NN * 128 * 2);
    ushort* h1 = (ushort*)take((size_t)NN * 128 * 2);
    ushort* h2 = (ushort*)take((size_t)NN * 128 * 2);
    ushort* meanbf = (ushort*)take((size_t)NN * 128 * 2);
    ushort* wbf = (ushort*)take(8 * 16384 * 2);

    Ptrs8 ps;
    ps.p[0] = Wl[0]; ps.p[1] = Wr[0]; ps.p[2] = Wl[1]; ps.p[3] = Wr[1];
    ps.p[4] = Wl[2]; ps.p[5] = Wr[2]; ps.p[6] = Wl[3]; ps.p[7] = Wr[3];

    // CSR via 2-level bucket sort: no global atomics, no memset, no fill.
    k_prep<<<CAST_B + CVTW_B + HIST_B, 256, 0, stream>>>(x, xbf, ps, wbf, ei,
                                                         ebuf, hcnt);
    k_scan1<<<1, 256, 0, stream>>>(hcnt, hoff, bb, row_ptr);
    k_scatter1<<<HIST_B, 256, 0, stream>>>(ebuf, hoff, ebuf2);
    k_sort2<<<NBK, 1024, 0, stream>>>(ebuf2, bb, row_ptr, col);

    const ushort* h = xbf;
    ushort* houts[4] = {h1, h2, h1, nullptr};  // final layer -> fp32 d_out
    for (int l = 0; l < 4; l++) {
        k_agg3<<<(NN + 3) / 4, 256, 0, stream>>>(h, row_ptr, col, meanbf);
        k_gemm_mfma<<<(NN + 127) / 128, 256, 0, stream>>>(
            meanbf, h, wbf + (size_t)(2 * l) * 16384,
            wbf + (size_t)(2 * l + 1) * 16384, bl[l], out, houts[l],
            l == 0 ? 1 : 0);
        h = houts[l];
    }
}